// Round 24
// baseline (490.675 us; speedup 1.0000x reference)
//
#include <hip/hip_runtime.h>
#include <stdint.h>

// ws_size: >=194,314,240 proven (R17); <269,750,000 (R0-14 bail) => almost surely
// 256MiB. This layout: 196,395,008 B. R18: plain block order. R21: never restyle
// proven GEMM text. R22/R23: gemm8p (256², counted vmcnt, swizzle) 0-conflict.
// R24: gi on gemm8p via xza concat; combine2z fuses enc2-combine + reparam.

#define B_SZ 4096
#define H_SZ 2048
#define Z_SZ 256

typedef __attribute__((ext_vector_type(4))) float f32x4;
typedef __attribute__((ext_vector_type(8))) short s16x8;

__device__ __forceinline__ uint16_t f2b(float f) {
  union { float f; uint32_t u; } v; v.f = f;
  uint32_t u = v.u;
  uint32_t r = (u + 0x7FFFu + ((u >> 16) & 1u)) >> 16;
  return (uint16_t)r;
}
__device__ __forceinline__ float b2f(uint16_t h) {
  union { uint32_t u; float f; } v; v.u = ((uint32_t)h) << 16; return v.f;
}
__device__ __forceinline__ float clip10(float v) { return fminf(fmaxf(v, -10.0f), 10.0f); }

// ---------------- fused multi-segment fp32->bf16 conversion ----------------
struct MC {
  const float* src[14];
  uint16_t* dst[14];
  int c8[14];
  int sld[14];
  int dld[14];
  int base[15];
};

__global__ __launch_bounds__(256) void multiconv(MC mc, int nseg, int total) {
  int gid = blockIdx.x * 256 + threadIdx.x;
  if (gid >= total) return;
  int s = 0;
  while (s + 1 < nseg && gid >= mc.base[s + 1]) ++s;
  int local = gid - mc.base[s];
  int c8 = mc.c8[s];
  int row = local / c8;
  int cg = local - row * c8;
  const f32x4* sp = (const f32x4*)(mc.src[s] + (size_t)row * mc.sld[s] + (size_t)cg * 8);
  f32x4 lo = sp[0], hi = sp[1];
  s16x8 p;
  p[0] = (short)f2b(lo[0]); p[1] = (short)f2b(lo[1]);
  p[2] = (short)f2b(lo[2]); p[3] = (short)f2b(lo[3]);
  p[4] = (short)f2b(hi[0]); p[5] = (short)f2b(hi[1]);
  p[6] = (short)f2b(hi[2]); p[7] = (short)f2b(hi[3]);
  *(s16x8*)(mc.dst[s] + (size_t)row * mc.dld[s] + (size_t)cg * 8) = p;
}

// biascat: [prior_b1 | b_hh | enc_b1 | dec_b1] (12288 fp32)
__global__ void biascat_kernel(const float* __restrict__ b0, const float* __restrict__ b1,
                               const float* __restrict__ b2, const float* __restrict__ b3,
                               float* __restrict__ dst) {
  int j = blockIdx.x * 256 + threadIdx.x;  // 12288
  float v;
  if (j < 2048) v = b0[j];
  else if (j < 8192) v = b1[j - 2048];
  else if (j < 10240) v = b2[j - 8192];
  else v = b3[j - 10240];
  dst[j] = v;
}

// ---------------- async global->LDS, 16B per lane ----------------
__device__ __forceinline__ void gload_lds16(const uint16_t* g, uint16_t* l) {
  __builtin_amdgcn_global_load_lds(
      (const __attribute__((address_space(1))) uint32_t*)g,
      (__attribute__((address_space(3))) uint32_t*)(uintptr_t)(void*)l,
      16, 0, 0);
}

// ======== 256x256 8-phase counted-vmcnt GEMM (R22/R23-proven text) ========
// C[M,N] = A @ W^T + bias[gcol]; relu iff gcol < splitN.
__global__ __launch_bounds__(512, 2)
void gemm8p(const uint16_t* __restrict__ A, int lda,
            const uint16_t* __restrict__ W,
            const float* __restrict__ bias,
            uint16_t* __restrict__ C, int ldc, int splitN,
            int Nt, int K) {
  __shared__ uint16_t Ab[2][2][8192];   // [dbuf][row-half][128*64]
  __shared__ uint16_t Bb[2][2][8192];
  const int NT = K >> 6;
  int mtile = blockIdx.x / Nt;
  int ntile = blockIdx.x - mtile * Nt;
  const int brow = mtile << 8, bcol = ntile << 8;
  const int tid = threadIdx.x;
  const int l = tid & 63;
  const int w = tid >> 6;
  const int wr = w >> 2, wcn = w & 3;   // 2(M) x 4(N) waves
  const int fr = l & 15, fq = l >> 4;
  const int sr0 = tid >> 3;             // staging row within 64-row stripe
  const int scg = tid & 7;              // staging col group
  const int dstoff = tid * 8;

  f32x4 acc[8][4] = {};

  auto stage_half = [&](int t, int q, int d) {
#pragma unroll
    for (int r = 0; r < 2; ++r) {
      int row = r * 64 + sr0;
      int col = (scg ^ (row & 7)) << 3;             // pre-swizzled source col
      if (q < 2)
        gload_lds16(A + (size_t)(brow + q * 128 + row) * lda + t * 64 + col,
                    &Ab[d][q][r * 4096 + dstoff]);
      else
        gload_lds16(W + (size_t)(bcol + (q - 2) * 128 + row) * K + t * 64 + col,
                    &Bb[d][q - 2][r * 4096 + dstoff]);
    }
  };

#pragma unroll
  for (int q = 0; q < 4; ++q) stage_half(0, q, 0);

  for (int t = 0; t < NT; ++t) {
    const int d = t & 1;
    const bool more = (t + 1 < NT);
    if (more) {
      stage_half(t + 1, 0, d ^ 1);
      asm volatile("s_waitcnt vmcnt(2)" ::: "memory");
    } else {
      asm volatile("s_waitcnt vmcnt(0)" ::: "memory");
    }
    __builtin_amdgcn_s_barrier();

#pragma unroll
    for (int q = 0; q < 4; ++q) {
      const int mh = q >> 1, nh = q & 1;
      if (q > 0 && more) stage_half(t + 1, q, d ^ 1);
      s16x8 fb[2][2];
#pragma unroll
      for (int nn = 0; nn < 2; ++nn)
#pragma unroll
        for (int ks = 0; ks < 2; ++ks) {
          int row = wcn * 64 + nh * 32 + nn * 16 + fr;
          int half = row >> 7, rl = row & 127;
          fb[nn][ks] = *(const s16x8*)&Bb[d][half]
              [rl * 64 + ((ks * 32 + fq * 8) ^ ((rl & 7) << 3))];
        }
      s16x8 fa[4][2];
#pragma unroll
      for (int mm = 0; mm < 4; ++mm)
#pragma unroll
        for (int ks = 0; ks < 2; ++ks) {
          int rl = mh * 64 + mm * 16 + fr;
          fa[mm][ks] = *(const s16x8*)&Ab[d][wr]
              [rl * 64 + ((ks * 32 + fq * 8) ^ ((rl & 7) << 3))];
        }
      __builtin_amdgcn_s_setprio(1);
#pragma unroll
      for (int mm = 0; mm < 4; ++mm)
#pragma unroll
        for (int nn = 0; nn < 2; ++nn)
#pragma unroll
          for (int ks = 0; ks < 2; ++ks)
            acc[mh * 4 + mm][nh * 2 + nn] = __builtin_amdgcn_mfma_f32_16x16x32_bf16(
                fa[mm][ks], fb[nn][ks], acc[mh * 4 + mm][nh * 2 + nn], 0, 0, 0);
      __builtin_amdgcn_s_setprio(0);
      __builtin_amdgcn_s_barrier();
    }
  }

#pragma unroll
  for (int m = 0; m < 8; ++m) {
    int grow = brow + wr * 128 + m * 16 + fq * 4;
#pragma unroll
    for (int n = 0; n < 4; ++n) {
      int gcol = bcol + wcn * 64 + n * 16 + fr;
      float bs = bias[gcol];
      bool doRelu = gcol < splitN;
#pragma unroll
      for (int i = 0; i < 4; ++i) {
        float v = acc[m][n][i] + bs;
        if (doRelu) v = fmaxf(v, 0.0f);
        C[(size_t)(grow + i) * ldc + gcol] = f2b(v);
      }
    }
  }
}

// ---- MFMA bf16 GEMM, split-A (R16/R21-proven text). ----
// EPI: 1 relu->C0 | 2 ->C0 | 3 col<splitN relu->C0 else ->C1 | 6 relu(acc+C0)->C0
template <int EPI>
__global__ __launch_bounds__(256)
void gemm_bt(const uint16_t* __restrict__ A0, int lda0, int ks1,
             const uint16_t* __restrict__ A1, int lda1, int ks2,
             const uint16_t* __restrict__ A2, int lda2,
             const uint16_t* __restrict__ W,
             const float* __restrict__ bias0, const float* __restrict__ bias1,
             uint16_t* __restrict__ C0, int ldc0, int splitN,
             uint16_t* __restrict__ C1, int ldc1,
             int Nt, int K) {
  __shared__ uint16_t As[128 * 64];
  __shared__ uint16_t Ws[128 * 64];
  int mtile = blockIdx.x / Nt;
  int ntile = blockIdx.x - mtile * Nt;
  const int row0 = mtile << 7, col0 = ntile << 7;
  const int t = threadIdx.x;
  const int w = t >> 6, l = t & 63;
  const int wr = w >> 1, wc = w & 1;
  const int sr = l >> 3, scg = l & 7;
  const int fr = l & 15, fq = l >> 4;

  f32x4 acc[4][4] = {};

  const uint16_t* Wbase = W + (size_t)(col0 + w * 32 + sr) * K + scg * 8;

  for (int k0 = 0; k0 < K; k0 += 64) {
    const uint16_t* ab; int ald, koff;   // wave-uniform region select
    if (k0 < ks1)      { ab = A0; ald = lda0; koff = k0; }
    else if (k0 < ks2) { ab = A1; ald = lda1; koff = k0 - ks1; }
    else               { ab = A2; ald = lda2; koff = k0 - ks2; }
    const uint16_t* Abase = ab + (size_t)(row0 + w * 32 + sr) * ald + koff + scg * 8;
#pragma unroll
    for (int j = 0; j < 4; ++j)
      gload_lds16(Abase + (size_t)(j * 8) * ald, &As[(w * 32 + j * 8) * 64]);
#pragma unroll
    for (int j = 0; j < 4; ++j)
      gload_lds16(Wbase + (size_t)(j * 8) * K + k0, &Ws[(w * 32 + j * 8) * 64]);
    __syncthreads();
#pragma unroll
    for (int ks = 0; ks < 2; ++ks) {
      s16x8 fa[4], fb[4];
#pragma unroll
      for (int m = 0; m < 4; ++m)
        fa[m] = *(const s16x8*)&As[(wr * 64 + m * 16 + fr) * 64 + ks * 32 + fq * 8];
#pragma unroll
      for (int n = 0; n < 4; ++n)
        fb[n] = *(const s16x8*)&Ws[(wc * 64 + n * 16 + fr) * 64 + ks * 32 + fq * 8];
#pragma unroll
      for (int m = 0; m < 4; ++m)
#pragma unroll
        for (int n = 0; n < 4; ++n)
          acc[m][n] = __builtin_amdgcn_mfma_f32_16x16x32_bf16(fa[m], fb[n], acc[m][n], 0, 0, 0);
    }
    __syncthreads();
  }

#pragma unroll
  for (int m = 0; m < 4; ++m) {
    int grow = row0 + wr * 64 + m * 16 + fq * 4;
#pragma unroll
    for (int n = 0; n < 4; ++n) {
      int gcol = col0 + wc * 64 + n * 16 + fr;
      bool first = (EPI != 3) || (gcol < splitN);
      float bs = first ? bias0[gcol] : bias1[gcol - splitN];
#pragma unroll
      for (int i = 0; i < 4; ++i) {
        size_t idx0 = (size_t)(grow + i) * ldc0 + gcol;
        if (EPI == 6) {
          float v6 = acc[m][n][i] + b2f(C0[idx0]);
          C0[idx0] = f2b(fmaxf(v6, 0.0f));
        } else {
          float v = acc[m][n][i] + bs;
          if (EPI == 1 || (EPI == 3 && first)) v = fmaxf(v, 0.0f);
          if (first)
            C0[idx0] = f2b(v);
          else
            C1[(size_t)(grow + i) * ldc1 + (gcol - splitN)] = f2b(v);
        }
      }
    }
  }
}

// ---- K-split GEMM (proven) ----
__global__ __launch_bounds__(256)
void gemm_ks(const uint16_t* __restrict__ A, int lda,
             const uint16_t* __restrict__ W, int Wld,
             float* __restrict__ P, int N,
             int Nt, int Khalf) {
  __shared__ uint16_t As[128 * 64];
  __shared__ uint16_t Ws[128 * 64];
  int bg = gridDim.x >> 1;
  int half = blockIdx.x >= bg;
  int bid = blockIdx.x - half * bg;
  int mtile = bid / Nt;
  int ntile = bid - mtile * Nt;
  const int row0 = mtile << 7, col0 = ntile << 7;
  const int t = threadIdx.x;
  const int w = t >> 6, l = t & 63;
  const int wr = w >> 1, wc = w & 1;
  const int sr = l >> 3, scg = l & 7;
  const int fr = l & 15, fq = l >> 4;

  f32x4 acc[4][4] = {};

  const uint16_t* Ab = A + half * Khalf;
  const uint16_t* Wb = W + half * Khalf;
  const uint16_t* Wbase = Wb + (size_t)(col0 + w * 32 + sr) * Wld + scg * 8;
  const uint16_t* Abase0 = Ab + (size_t)(row0 + w * 32 + sr) * lda + scg * 8;

  for (int k0 = 0; k0 < Khalf; k0 += 64) {
#pragma unroll
    for (int j = 0; j < 4; ++j)
      gload_lds16(Abase0 + (size_t)(j * 8) * lda + k0, &As[(w * 32 + j * 8) * 64]);
#pragma unroll
    for (int j = 0; j < 4; ++j)
      gload_lds16(Wbase + (size_t)(j * 8) * Wld + k0, &Ws[(w * 32 + j * 8) * 64]);
    __syncthreads();
#pragma unroll
    for (int ks = 0; ks < 2; ++ks) {
      s16x8 fa[4], fb[4];
#pragma unroll
      for (int m = 0; m < 4; ++m)
        fa[m] = *(const s16x8*)&As[(wr * 64 + m * 16 + fr) * 64 + ks * 32 + fq * 8];
#pragma unroll
      for (int n = 0; n < 4; ++n)
        fb[n] = *(const s16x8*)&Ws[(wc * 64 + n * 16 + fr) * 64 + ks * 32 + fq * 8];
#pragma unroll
      for (int m = 0; m < 4; ++m)
#pragma unroll
        for (int n = 0; n < 4; ++n)
          acc[m][n] = __builtin_amdgcn_mfma_f32_16x16x32_bf16(fa[m], fb[n], acc[m][n], 0, 0, 0);
    }
    __syncthreads();
  }

  float* Pf = P + (size_t)half * B_SZ * N;
#pragma unroll
  for (int m = 0; m < 4; ++m) {
    int grow = row0 + wr * 64 + m * 16 + fq * 4;
#pragma unroll
    for (int n = 0; n < 4; ++n) {
      int gcol = col0 + wc * 64 + n * 16 + fr;
#pragma unroll
      for (int i = 0; i < 4; ++i)
        Pf[(size_t)(grow + i) * N + gcol] = acc[m][n][i];
    }
  }
}

// combiner: dst = bf16(P0 + P1 + bias), N power of two
__global__ __launch_bounds__(256)
void combine2(const float* __restrict__ P, const float* __restrict__ bias,
              uint16_t* __restrict__ dst, int N, int total4) {
  int i = blockIdx.x * 256 + threadIdx.x;
  if (i >= total4) return;
  size_t idx = (size_t)i * 4;
  const float* P1 = P + (size_t)B_SZ * N;
  f32x4 a = *(const f32x4*)(P + idx);
  f32x4 b = *(const f32x4*)(P1 + idx);
  int col = (int)(idx & (size_t)(N - 1));
#pragma unroll
  for (int k = 0; k < 4; ++k)
    dst[idx + k] = f2b(a[k] + b[k] + bias[col + k]);
}

// combine2z: enc2-combiner fused with reparameterization.
// estats = bf16(P0+P1+b); z = mu + eps*exp(0.5*clip(lq)); z also -> xza col 512+j.
__global__ __launch_bounds__(256)
void combine2z(const float* __restrict__ P, const float* __restrict__ bias,
               const float* __restrict__ eps,
               uint16_t* __restrict__ estats,
               float* __restrict__ oz, float* __restrict__ omu, float* __restrict__ olq,
               uint16_t* __restrict__ xza) {
  int i = blockIdx.x * 256 + threadIdx.x;  // B*Z
  int b = i >> 8, j = i & 255;
  const float* P1 = P + (size_t)B_SZ * 512;
  size_t i0 = (size_t)b * 512 + j;
  size_t i1 = i0 + 256;
  float mu = P[i0] + P1[i0] + bias[j];
  float lq = P[i1] + P1[i1] + bias[j + 256];
  estats[i0] = f2b(mu);
  estats[i1] = f2b(lq);
  float lqc = clip10(lq);
  float z = mu + eps[i] * __expf(0.5f * lqc);
  oz[i] = z; omu[i] = mu; olq[i] = lqc;
  xza[(size_t)b * 832 + 512 + j] = f2b(z);
}

__device__ __forceinline__ float block_sum256(float v) {
  __shared__ float ps[4];
#pragma unroll
  for (int o = 32; o > 0; o >>= 1) v += __shfl_xor(v, o, 64);
  int l = threadIdx.x & 63, w = threadIdx.x >> 6;
  if (l == 0) ps[w] = v;
  __syncthreads();
  float r = ps[0] + ps[1] + ps[2] + ps[3];
  __syncthreads();
  return r;
}

// ---------------- epilogue: GRU + nll + kl ----------------
__global__ __launch_bounds__(256)
void gru_fused_t1(const uint16_t* __restrict__ gi, int ldgi,
                  const uint16_t* __restrict__ gh, int ldgh,
                  const float* __restrict__ hp, const float* __restrict__ x,
                  const uint16_t* __restrict__ dec, const uint16_t* __restrict__ pst,
                  const uint16_t* __restrict__ es,
                  float* __restrict__ out_h, float* __restrict__ out_nll,
                  float* __restrict__ out_kl) {
  int b = blockIdx.x, t = threadIdx.x;
  size_t gbi = (size_t)b * ldgi + (size_t)t * 8;
  size_t gbh = (size_t)b * ldgh + (size_t)t * 8;
  s16x8 ir = *(const s16x8*)(gi + gbi);
  s16x8 iz = *(const s16x8*)(gi + gbi + 2048);
  s16x8 inn = *(const s16x8*)(gi + gbi + 4096);
  s16x8 hr = *(const s16x8*)(gh + gbh);
  s16x8 hz = *(const s16x8*)(gh + gbh + 2048);
  s16x8 hn = *(const s16x8*)(gh + gbh + 4096);
  size_t hbase = (size_t)b * 2048 + (size_t)t * 8;
  f32x4 h0 = *(const f32x4*)(hp + hbase);
  f32x4 h1v = *(const f32x4*)(hp + hbase + 4);
  f32x4 o0, o1;
#pragma unroll
  for (int e = 0; e < 8; ++e) {
    float r = 1.f / (1.f + __expf(-(b2f((uint16_t)ir[e]) + b2f((uint16_t)hr[e]))));
    float zg = 1.f / (1.f + __expf(-(b2f((uint16_t)iz[e]) + b2f((uint16_t)hz[e]))));
    float nv = b2f((uint16_t)inn[e]) + r * b2f((uint16_t)hn[e]);
    float t2 = __expf(-2.f * fabsf(nv));
    float n = (1.f - t2) / (1.f + t2);
    n = (nv >= 0.f) ? n : -n;
    float hv = (e < 4) ? h0[e] : h1v[e - 4];
    float o = (1.f - zg) * n + zg * hv;
    if (e < 4) o0[e] = o; else o1[e - 4] = o;
  }
  *(f32x4*)(out_h + hbase) = o0;
  *(f32x4*)(out_h + hbase + 4) = o1;

  float s = 0.f;
#pragma unroll
  for (int rr = 0; rr < 2; ++rr) {
    int j = t + rr * 256;
    float mu = b2f(dec[(size_t)b * 1024 + j]);
    float lx = clip10(b2f(dec[(size_t)b * 1024 + 512 + j]));
    float d = x[(size_t)b * 512 + j] - mu;
    s += d * d * __expf(-lx) + lx;
  }
  s = block_sum256(s);
  if (t == 0) out_nll[b] = 0.5f * s;

  float mu_p = b2f(pst[(size_t)b * 512 + t]);
  float lp = b2f(pst[(size_t)b * 512 + 256 + t]);
  float mu_q = b2f(es[(size_t)b * 512 + t]);
  float lq = clip10(b2f(es[(size_t)b * 512 + 256 + t]));
  float dq = mu_q - mu_p;
  float enl = __expf(-lp);
  float kv = dq * dq * enl + __expf(lq) * enl + (lp - lq) - 1.0f;
  kv = block_sum256(kv);
  if (t == 0) out_kl[b] = 0.5f * kv;
}

// ================= tier 2 fallback: naive fp32 sliced pipeline =================
template <int MODE>
__global__ __launch_bounds__(256)
void gemm_nv(const float* __restrict__ A0, int ld0, int s1,
             const float* __restrict__ A1, int ld1, int s2,
             const float* __restrict__ A2, int ld2,
             const float* __restrict__ W, const float* __restrict__ bias,
             float* __restrict__ C, int N, int K) {
  int nb = N >> 8;
  int m = blockIdx.x / nb;
  int n = (blockIdx.x - m * nb) * 256 + threadIdx.x;
  const float* w = W + (size_t)n * K;
  float acc = 0.f;
  int k = 0;
  for (; k < s1; ++k) acc += A0[(size_t)m * ld0 + k] * w[k];
  for (; k < s2; ++k) acc += A1[(size_t)m * ld1 + (k - s1)] * w[k];
  for (; k < K; ++k) acc += A2[(size_t)m * ld2 + (k - s2)] * w[k];
  acc += bias[n];
  if (MODE == 1) acc = fmaxf(acc, 0.f);
  C[(size_t)m * N + n] = acc;
}

__global__ void z_nv(const float* __restrict__ ests, const float* __restrict__ eps,
                     float* __restrict__ oz, float* __restrict__ omu,
                     float* __restrict__ olq, float* __restrict__ zs, int row0, int nR) {
  int i = blockIdx.x * 256 + threadIdx.x;
  if (i >= nR * 256) return;
  int bl = i >> 8, j = i & 255;
  size_t g = (size_t)(row0 + bl) * 256 + j;
  float mu = ests[(size_t)bl * 512 + j];
  float lq = clip10(ests[(size_t)bl * 512 + 256 + j]);
  float z = mu + eps[g] * __expf(0.5f * lq);
  oz[g] = z; omu[g] = mu; olq[g] = lq;
  zs[(size_t)bl * 256 + j] = z;
}

__global__ void nll_nv(const float* __restrict__ x, const float* __restrict__ decs,
                       float* __restrict__ out, int row0) {
  int bl = blockIdx.x, l = threadIdx.x;
  int gb = row0 + bl;
  float s = 0.f;
  for (int j = l; j < 512; j += 64) {
    float mu = decs[(size_t)bl * 1024 + j];
    float lx = clip10(decs[(size_t)bl * 1024 + 512 + j]);
    float d = x[(size_t)gb * 512 + j] - mu;
    s += d * d * __expf(-lx) + lx;
  }
#pragma unroll
  for (int o = 32; o > 0; o >>= 1) s += __shfl_xor(s, o, 64);
  if (l == 0) out[gb] = 0.5f * s;
}

__global__ void kl_nv(const float* __restrict__ psts, const float* __restrict__ ests,
                      float* __restrict__ out, int row0) {
  int bl = blockIdx.x, l = threadIdx.x;
  int gb = row0 + bl;
  float s = 0.f;
  for (int j = l; j < 256; j += 64) {
    float mu_p = psts[(size_t)bl * 512 + j];
    float lp = psts[(size_t)bl * 512 + 256 + j];
    float mu_q = ests[(size_t)bl * 512 + j];
    float lq = clip10(ests[(size_t)bl * 512 + 256 + j]);
    float d = mu_q - mu_p;
    float enl = __expf(-lp);
    s += d * d * enl + __expf(lq) * enl + (lp - lq) - 1.0f;
  }
#pragma unroll
  for (int o = 32; o > 0; o >>= 1) s += __shfl_xor(s, o, 64);
  if (l == 0) out[gb] = 0.5f * s;
}

__global__ void gru_nv(const float* __restrict__ gis, const float* __restrict__ ghs,
                       const float* __restrict__ hp, float* __restrict__ ho,
                       int row0, int nR) {
  int i = blockIdx.x * 256 + threadIdx.x;
  if (i >= nR * 2048) return;
  int bl = i >> 11, j = i & 2047;
  size_t lb = (size_t)bl * 6144 + j;
  float r = 1.f / (1.f + __expf(-(gis[lb] + ghs[lb])));
  float zg = 1.f / (1.f + __expf(-(gis[lb + 2048] + ghs[lb + 2048])));
  float nv = gis[lb + 4096] + r * ghs[lb + 4096];
  float t2 = __expf(-2.f * fabsf(nv));
  float n = (1.f - t2) / (1.f + t2);
  n = (nv >= 0.f) ? n : -n;
  size_t g = (size_t)(row0 + bl) * 2048 + j;
  ho[g] = (1.f - zg) * n + zg * hp[g];
}

// ---------------- host ----------------
extern "C" void kernel_launch(void* const* d_in, const int* in_sizes, int n_in,
                              void* d_out, int out_size, void* d_ws, size_t ws_size,
                              hipStream_t stream) {
  const float* x_t = (const float*)d_in[0];
  const float* a_prev = (const float*)d_in[1];
  const float* h_prev = (const float*)d_in[2];
  const float* eps = (const float*)d_in[3];
  const float* prior_w1 = (const float*)d_in[4];
  const float* prior_b1 = (const float*)d_in[5];
  const float* prior_w2 = (const float*)d_in[6];
  const float* prior_b2 = (const float*)d_in[7];
  const float* enc_w1 = (const float*)d_in[8];
  const float* enc_b1 = (const float*)d_in[9];
  const float* enc_w2 = (const float*)d_in[10];
  const float* enc_b2 = (const float*)d_in[11];
  const float* dec_w1 = (const float*)d_in[12];
  const float* dec_b1 = (const float*)d_in[13];
  const float* dec_w2 = (const float*)d_in[14];
  const float* dec_b2 = (const float*)d_in[15];
  const float* w_ih = (const float*)d_in[16];
  const float* w_hh = (const float*)d_in[17];
  const float* b_ih = (const float*)d_in[18];
  const float* b_hh = (const float*)d_in[19];

  float* out = (float*)d_out;
  float* out_h = out;
  float* out_nll = out + (size_t)B_SZ * H_SZ;
  float* out_kl = out_nll + B_SZ;
  float* out_z = out_kl + B_SZ;
  float* out_mu = out_z + (size_t)B_SZ * Z_SZ;
  float* out_lq = out_mu + (size_t)B_SZ * Z_SZ;

  char* ws = (char*)d_ws;
  size_t off = 0;
  auto alloc = [&](size_t bytes) {
    void* p = ws + off;
    off += (bytes + 255) & ~(size_t)255;
    return p;
  };

  const size_t T1_DEMAND = 196500000;  // layout sums to 196,395,008

  if (ws_size >= T1_DEMAND) {
    // =========== tier 1: mega on gemm8p + gi on gemm8p ===========
    uint16_t* wmega = (uint16_t*)alloc((size_t)12288 * 2048 * 2);  // dead after mega
    uint16_t* wih = (uint16_t*)alloc((size_t)6144 * 832 * 2);
    uint16_t* wx_enc = (uint16_t*)alloc((size_t)2048 * 512 * 2);
    uint16_t* wz_dec = (uint16_t*)alloc((size_t)2048 * 256 * 2);
    uint16_t* pw2 = (uint16_t*)alloc((size_t)512 * 2048 * 2);
    uint16_t* ew2 = (uint16_t*)alloc((size_t)512 * 2048 * 2);
    uint16_t* dw2 = (uint16_t*)alloc((size_t)1024 * 2048 * 2);
    uint16_t* xza = (uint16_t*)alloc((size_t)B_SZ * 832 * 2);     // [x|z|a] concat
    uint16_t* hbuf = (uint16_t*)alloc((size_t)B_SZ * 2048 * 2);   // dead after mega
    uint16_t* megaC = (uint16_t*)alloc((size_t)B_SZ * 12288 * 2); // [h1p|gh|ench|dech]
    float* biascat = (float*)alloc(12288 * 4);
    // overlays (stream-ordered safe):
    float* Pbuf = (float*)wmega;                // K-split partials, pre-gi
    uint16_t* gi = wmega;                       // written after last Pbuf use
    uint16_t* pstats = hbuf;                    // after mega
    uint16_t* estats = hbuf + (size_t)2097152;
    uint16_t* decout = pw2;                     // pw2+ew2+dw2 span (dead/post-read)

    // ---- single fused conversion launch (12 segments) ----
    MC mc;
    int nseg = 0, acc = 0;
    auto seg = [&](const float* s, uint16_t* d, int R, int C, int sld, int dld) {
      mc.src[nseg] = s; mc.dst[nseg] = d; mc.c8[nseg] = C / 8;
      mc.sld[nseg] = sld; mc.dld[nseg] = dld; mc.base[nseg] = acc;
      acc += R * (C / 8); ++nseg;
    };
    seg(prior_w1, wmega, 2048, 2048, 2048, 2048);
    seg(w_hh, wmega + (size_t)2048 * 2048, 6144, 2048, 2048, 2048);
    seg(enc_w1 + 512, wmega + (size_t)8192 * 2048, 2048, 2048, 2560, 2048);
    seg(dec_w1 + 256, wmega + (size_t)10240 * 2048, 2048, 2048, 2304, 2048);
    seg(enc_w1, wx_enc, 2048, 512, 2560, 512);
    seg(dec_w1, wz_dec, 2048, 256, 2304, 256);
    seg(prior_w2, pw2, 512, 2048, 2048, 2048);
    seg(enc_w2, ew2, 512, 2048, 2048, 2048);
    seg(dec_w2, dw2, 1024, 2048, 2048, 2048);
    seg(w_ih, wih, 6144, 832, 832, 832);
    seg(x_t, xza, B_SZ, 512, 512, 832);
    seg(a_prev, xza + 768, B_SZ, 64, 64, 832);
    seg(h_prev, hbuf, B_SZ, 2048, 2048, 2048);
    mc.base[nseg] = acc;
    multiconv<<<dim3((acc + 255) / 256), dim3(256), 0, stream>>>(mc, nseg, acc);
    biascat_kernel<<<dim3(48), dim3(256), 0, stream>>>(prior_b1, b_hh, enc_b1, dec_b1, biascat);

    // mega: megaC[4096,12288] = h @ wmega^T + biascat (relu cols<2048), 8-phase
    gemm8p<<<dim3((B_SZ / 256) * 48), dim3(512), 0, stream>>>(
        hbuf, 2048, wmega, biascat, megaC, 12288, 2048, 48, 2048);
    // prior2 (K-split x2): A = megaC cols 0..2047
    gemm_ks<<<dim3((B_SZ / 128) * 4 * 2), dim3(256), 0, stream>>>(
        megaC, 12288, pw2, 2048, Pbuf, 512, 4, 1024);
    combine2<<<dim3(B_SZ * 512 / 4 / 256), dim3(256), 0, stream>>>(
        Pbuf, prior_b2, pstats, 512, B_SZ * 512 / 4);
    // enc1x: relu(x @ wx^T + ench_partial) in-place at megaC+8192 (EPI6)
    gemm_bt<6><<<dim3((B_SZ / 128) * 16), dim3(256), 0, stream>>>(
        xza, 832, 512, xza, 832, 512, xza, 832, wx_enc,
        enc_b1, enc_b1, megaC + 8192, 12288, 2048, megaC + 8192, 12288, 16, 512);
    // enc2 (K-split x2) then fused combine+reparam (writes z into xza col 512)
    gemm_ks<<<dim3((B_SZ / 128) * 4 * 2), dim3(256), 0, stream>>>(
        megaC + 8192, 12288, ew2, 2048, Pbuf, 512, 4, 1024);
    combine2z<<<dim3(B_SZ * Z_SZ / 256), dim3(256), 0, stream>>>(
        Pbuf, enc_b2, eps, estats, out_z, out_mu, out_lq, xza);
    // dec1x: relu(z @ wz^T + dech_partial) in-place at megaC+10240 (EPI6)
    gemm_bt<6><<<dim3((B_SZ / 128) * 16), dim3(256), 0, stream>>>(
        xza + 512, 832, 256, xza + 512, 832, 256, xza + 512, 832, wz_dec,
        dec_b1, dec_b1, megaC + 10240, 12288, 2048, megaC + 10240, 12288, 16, 256);
    // dec2 (K-split x2) -> decout
    gemm_ks<<<dim3((B_SZ / 128) * 8 * 2), dim3(256), 0, stream>>>(
        megaC + 10240, 12288, dw2, 2048, Pbuf, 1024, 8, 1024);
    combine2<<<dim3(B_SZ * 1024 / 4 / 256), dim3(256), 0, stream>>>(
        Pbuf, dec_b2, decout, 1024, B_SZ * 1024 / 4);
    // gi: xza @ w_ih^T + b on gemm8p (K=832, 13 tiles; no relu; after Pbuf dead)
    gemm8p<<<dim3((B_SZ / 256) * 24), dim3(512), 0, stream>>>(
        xza, 832, wih, b_ih, gi, 6144, 0, 24, 832);
    // epilogue: gh lives at megaC cols 2048.. (stride 12288)
    gru_fused_t1<<<dim3(B_SZ), dim3(256), 0, stream>>>(
        gi, 6144, megaC + 2048, 12288, h_prev, x_t, decout, pstats, estats,
        out_h, out_nll, out_kl);
  } else {
    // =========== tier 2: naive fp32 sliced ===========
    int R = 512;
    while (R > 32 && (size_t)R * 66560 + 4096 > ws_size) R >>= 1;
    float* h1s = (float*)alloc((size_t)R * 2048 * 4);
    float* psts = (float*)alloc((size_t)R * 512 * 4);
    float* ests = (float*)alloc((size_t)R * 512 * 4);
    float* decs = (float*)alloc((size_t)R * 1024 * 4);
    float* zs = (float*)alloc((size_t)R * 256 * 4);
    float* gis = (float*)alloc((size_t)R * 6144 * 4);
    float* ghs = (float*)alloc((size_t)R * 6144 * 4);
    const float* dummy = x_t;

    auto nv = [&](const float* A0, int ld0, int s1, const float* A1, int ld1, int s2,
                  const float* A2, int ld2, const float* W, const float* bias,
                  float* C, int M, int N, int K, int relu) {
      dim3 grid(M * (N / 256));
      if (relu)
        gemm_nv<1><<<grid, dim3(256), 0, stream>>>(A0, ld0, s1, A1, ld1, s2, A2, ld2, W, bias, C, N, K);
      else
        gemm_nv<0><<<grid, dim3(256), 0, stream>>>(A0, ld0, s1, A1, ld1, s2, A2, ld2, W, bias, C, N, K);
    };

    for (int s = 0; s < B_SZ / R; ++s) {
      int r0 = s * R;
      const float* xs = x_t + (size_t)r0 * 512;
      const float* hs = h_prev + (size_t)r0 * 2048;
      const float* as = a_prev + (size_t)r0 * 64;
      nv(hs, 2048, 2048, dummy, 0, 2048, dummy, 0, prior_w1, prior_b1, h1s, R, 2048, 2048, 1);
      nv(h1s, 2048, 2048, dummy, 0, 2048, dummy, 0, prior_w2, prior_b2, psts, R, 512, 2048, 0);
      nv(xs, 512, 512, hs, 2048, 2560, dummy, 0, enc_w1, enc_b1, h1s, R, 2048, 2560, 1);
      nv(h1s, 2048, 2048, dummy, 0, 2048, dummy, 0, enc_w2, enc_b2, ests, R, 512, 2048, 0);
      z_nv<<<dim3((R * 256 + 255) / 256), dim3(256), 0, stream>>>(
          ests, eps, out_z, out_mu, out_lq, zs, r0, R);
      nv(zs, 256, 256, hs, 2048, 2304, dummy, 0, dec_w1, dec_b1, h1s, R, 2048, 2304, 1);
      nv(h1s, 2048, 2048, dummy, 0, 2048, dummy, 0, dec_w2, dec_b2, decs, R, 1024, 2048, 0);
      nv(hs, 2048, 2048, dummy, 0, 2048, dummy, 0, w_hh, b_hh, ghs, R, 6144, 2048, 0);
      nv(xs, 512, 512, zs, 256, 768, as, 64, w_ih, b_ih, gis, R, 6144, 832, 0);
      nll_nv<<<dim3(R), dim3(64), 0, stream>>>(x_t, decs, out_nll, r0);
      kl_nv<<<dim3(R), dim3(64), 0, stream>>>(psts, ests, out_kl, r0);
      gru_nv<<<dim3((R * 2048 + 255) / 256), dim3(256), 0, stream>>>(
          gis, ghs, h_prev, out_h, r0, R);
    }
  }
}

// Round 25
// 460.278 us; speedup vs baseline: 1.0660x; 1.0660x over previous
//
#include <hip/hip_runtime.h>
#include <stdint.h>

// ws_size ∈ [196.5MB proven avail (R24 ran 196.4MB), 269.7MB). R18: plain block
// order. R21: never restyle proven GEMM text. R22/23: gemm8p 0-conflict 912TF.
// R24 lesson: gemm8p only for grid>=2xCU and deep K; gi stays on gemm_bt.
// R25: gi reverted to gemm_bt (xza single-region); prior2+enc2 fused into one
// dual K-split dispatch (gemm_ks2).

#define B_SZ 4096
#define H_SZ 2048
#define Z_SZ 256

typedef __attribute__((ext_vector_type(4))) float f32x4;
typedef __attribute__((ext_vector_type(8))) short s16x8;

__device__ __forceinline__ uint16_t f2b(float f) {
  union { float f; uint32_t u; } v; v.f = f;
  uint32_t u = v.u;
  uint32_t r = (u + 0x7FFFu + ((u >> 16) & 1u)) >> 16;
  return (uint16_t)r;
}
__device__ __forceinline__ float b2f(uint16_t h) {
  union { uint32_t u; float f; } v; v.u = ((uint32_t)h) << 16; return v.f;
}
__device__ __forceinline__ float clip10(float v) { return fminf(fmaxf(v, -10.0f), 10.0f); }

// ---------------- fused multi-segment fp32->bf16 conversion ----------------
struct MC {
  const float* src[14];
  uint16_t* dst[14];
  int c8[14];
  int sld[14];
  int dld[14];
  int base[15];
};

__global__ __launch_bounds__(256) void multiconv(MC mc, int nseg, int total) {
  int gid = blockIdx.x * 256 + threadIdx.x;
  if (gid >= total) return;
  int s = 0;
  while (s + 1 < nseg && gid >= mc.base[s + 1]) ++s;
  int local = gid - mc.base[s];
  int c8 = mc.c8[s];
  int row = local / c8;
  int cg = local - row * c8;
  const f32x4* sp = (const f32x4*)(mc.src[s] + (size_t)row * mc.sld[s] + (size_t)cg * 8);
  f32x4 lo = sp[0], hi = sp[1];
  s16x8 p;
  p[0] = (short)f2b(lo[0]); p[1] = (short)f2b(lo[1]);
  p[2] = (short)f2b(lo[2]); p[3] = (short)f2b(lo[3]);
  p[4] = (short)f2b(hi[0]); p[5] = (short)f2b(hi[1]);
  p[6] = (short)f2b(hi[2]); p[7] = (short)f2b(hi[3]);
  *(s16x8*)(mc.dst[s] + (size_t)row * mc.dld[s] + (size_t)cg * 8) = p;
}

// biascat: [prior_b1 | b_hh | enc_b1 | dec_b1] (12288 fp32)
__global__ void biascat_kernel(const float* __restrict__ b0, const float* __restrict__ b1,
                               const float* __restrict__ b2, const float* __restrict__ b3,
                               float* __restrict__ dst) {
  int j = blockIdx.x * 256 + threadIdx.x;  // 12288
  float v;
  if (j < 2048) v = b0[j];
  else if (j < 8192) v = b1[j - 2048];
  else if (j < 10240) v = b2[j - 8192];
  else v = b3[j - 10240];
  dst[j] = v;
}

// ---------------- async global->LDS, 16B per lane ----------------
__device__ __forceinline__ void gload_lds16(const uint16_t* g, uint16_t* l) {
  __builtin_amdgcn_global_load_lds(
      (const __attribute__((address_space(1))) uint32_t*)g,
      (__attribute__((address_space(3))) uint32_t*)(uintptr_t)(void*)l,
      16, 0, 0);
}

// ======== 256x256 8-phase counted-vmcnt GEMM (R22/R23-proven text) ========
// C[M,N] = A @ W^T + bias[gcol]; relu iff gcol < splitN.
__global__ __launch_bounds__(512, 2)
void gemm8p(const uint16_t* __restrict__ A, int lda,
            const uint16_t* __restrict__ W,
            const float* __restrict__ bias,
            uint16_t* __restrict__ C, int ldc, int splitN,
            int Nt, int K) {
  __shared__ uint16_t Ab[2][2][8192];   // [dbuf][row-half][128*64]
  __shared__ uint16_t Bb[2][2][8192];
  const int NT = K >> 6;
  int mtile = blockIdx.x / Nt;
  int ntile = blockIdx.x - mtile * Nt;
  const int brow = mtile << 8, bcol = ntile << 8;
  const int tid = threadIdx.x;
  const int l = tid & 63;
  const int w = tid >> 6;
  const int wr = w >> 2, wcn = w & 3;   // 2(M) x 4(N) waves
  const int fr = l & 15, fq = l >> 4;
  const int sr0 = tid >> 3;             // staging row within 64-row stripe
  const int scg = tid & 7;              // staging col group
  const int dstoff = tid * 8;

  f32x4 acc[8][4] = {};

  auto stage_half = [&](int t, int q, int d) {
#pragma unroll
    for (int r = 0; r < 2; ++r) {
      int row = r * 64 + sr0;
      int col = (scg ^ (row & 7)) << 3;             // pre-swizzled source col
      if (q < 2)
        gload_lds16(A + (size_t)(brow + q * 128 + row) * lda + t * 64 + col,
                    &Ab[d][q][r * 4096 + dstoff]);
      else
        gload_lds16(W + (size_t)(bcol + (q - 2) * 128 + row) * K + t * 64 + col,
                    &Bb[d][q - 2][r * 4096 + dstoff]);
    }
  };

#pragma unroll
  for (int q = 0; q < 4; ++q) stage_half(0, q, 0);

  for (int t = 0; t < NT; ++t) {
    const int d = t & 1;
    const bool more = (t + 1 < NT);
    if (more) {
      stage_half(t + 1, 0, d ^ 1);
      asm volatile("s_waitcnt vmcnt(2)" ::: "memory");
    } else {
      asm volatile("s_waitcnt vmcnt(0)" ::: "memory");
    }
    __builtin_amdgcn_s_barrier();

#pragma unroll
    for (int q = 0; q < 4; ++q) {
      const int mh = q >> 1, nh = q & 1;
      if (q > 0 && more) stage_half(t + 1, q, d ^ 1);
      s16x8 fb[2][2];
#pragma unroll
      for (int nn = 0; nn < 2; ++nn)
#pragma unroll
        for (int ks = 0; ks < 2; ++ks) {
          int row = wcn * 64 + nh * 32 + nn * 16 + fr;
          int half = row >> 7, rl = row & 127;
          fb[nn][ks] = *(const s16x8*)&Bb[d][half]
              [rl * 64 + ((ks * 32 + fq * 8) ^ ((rl & 7) << 3))];
        }
      s16x8 fa[4][2];
#pragma unroll
      for (int mm = 0; mm < 4; ++mm)
#pragma unroll
        for (int ks = 0; ks < 2; ++ks) {
          int rl = mh * 64 + mm * 16 + fr;
          fa[mm][ks] = *(const s16x8*)&Ab[d][wr]
              [rl * 64 + ((ks * 32 + fq * 8) ^ ((rl & 7) << 3))];
        }
      __builtin_amdgcn_s_setprio(1);
#pragma unroll
      for (int mm = 0; mm < 4; ++mm)
#pragma unroll
        for (int nn = 0; nn < 2; ++nn)
#pragma unroll
          for (int ks = 0; ks < 2; ++ks)
            acc[mh * 4 + mm][nh * 2 + nn] = __builtin_amdgcn_mfma_f32_16x16x32_bf16(
                fa[mm][ks], fb[nn][ks], acc[mh * 4 + mm][nh * 2 + nn], 0, 0, 0);
      __builtin_amdgcn_s_setprio(0);
      __builtin_amdgcn_s_barrier();
    }
  }

#pragma unroll
  for (int m = 0; m < 8; ++m) {
    int grow = brow + wr * 128 + m * 16 + fq * 4;
#pragma unroll
    for (int n = 0; n < 4; ++n) {
      int gcol = bcol + wcn * 64 + n * 16 + fr;
      float bs = bias[gcol];
      bool doRelu = gcol < splitN;
#pragma unroll
      for (int i = 0; i < 4; ++i) {
        float v = acc[m][n][i] + bs;
        if (doRelu) v = fmaxf(v, 0.0f);
        C[(size_t)(grow + i) * ldc + gcol] = f2b(v);
      }
    }
  }
}

// ---- MFMA bf16 GEMM, split-A (R16/R21-proven text). ----
// EPI: 1 relu->C0 | 2 ->C0 | 3 col<splitN relu->C0 else ->C1 | 6 relu(acc+C0)->C0
template <int EPI>
__global__ __launch_bounds__(256)
void gemm_bt(const uint16_t* __restrict__ A0, int lda0, int ks1,
             const uint16_t* __restrict__ A1, int lda1, int ks2,
             const uint16_t* __restrict__ A2, int lda2,
             const uint16_t* __restrict__ W,
             const float* __restrict__ bias0, const float* __restrict__ bias1,
             uint16_t* __restrict__ C0, int ldc0, int splitN,
             uint16_t* __restrict__ C1, int ldc1,
             int Nt, int K) {
  __shared__ uint16_t As[128 * 64];
  __shared__ uint16_t Ws[128 * 64];
  int mtile = blockIdx.x / Nt;
  int ntile = blockIdx.x - mtile * Nt;
  const int row0 = mtile << 7, col0 = ntile << 7;
  const int t = threadIdx.x;
  const int w = t >> 6, l = t & 63;
  const int wr = w >> 1, wc = w & 1;
  const int sr = l >> 3, scg = l & 7;
  const int fr = l & 15, fq = l >> 4;

  f32x4 acc[4][4] = {};

  const uint16_t* Wbase = W + (size_t)(col0 + w * 32 + sr) * K + scg * 8;

  for (int k0 = 0; k0 < K; k0 += 64) {
    const uint16_t* ab; int ald, koff;   // wave-uniform region select
    if (k0 < ks1)      { ab = A0; ald = lda0; koff = k0; }
    else if (k0 < ks2) { ab = A1; ald = lda1; koff = k0 - ks1; }
    else               { ab = A2; ald = lda2; koff = k0 - ks2; }
    const uint16_t* Abase = ab + (size_t)(row0 + w * 32 + sr) * ald + koff + scg * 8;
#pragma unroll
    for (int j = 0; j < 4; ++j)
      gload_lds16(Abase + (size_t)(j * 8) * ald, &As[(w * 32 + j * 8) * 64]);
#pragma unroll
    for (int j = 0; j < 4; ++j)
      gload_lds16(Wbase + (size_t)(j * 8) * K + k0, &Ws[(w * 32 + j * 8) * 64]);
    __syncthreads();
#pragma unroll
    for (int ks = 0; ks < 2; ++ks) {
      s16x8 fa[4], fb[4];
#pragma unroll
      for (int m = 0; m < 4; ++m)
        fa[m] = *(const s16x8*)&As[(wr * 64 + m * 16 + fr) * 64 + ks * 32 + fq * 8];
#pragma unroll
      for (int n = 0; n < 4; ++n)
        fb[n] = *(const s16x8*)&Ws[(wc * 64 + n * 16 + fr) * 64 + ks * 32 + fq * 8];
#pragma unroll
      for (int m = 0; m < 4; ++m)
#pragma unroll
        for (int n = 0; n < 4; ++n)
          acc[m][n] = __builtin_amdgcn_mfma_f32_16x16x32_bf16(fa[m], fb[n], acc[m][n], 0, 0, 0);
    }
    __syncthreads();
  }

#pragma unroll
  for (int m = 0; m < 4; ++m) {
    int grow = row0 + wr * 64 + m * 16 + fq * 4;
#pragma unroll
    for (int n = 0; n < 4; ++n) {
      int gcol = col0 + wc * 64 + n * 16 + fr;
      bool first = (EPI != 3) || (gcol < splitN);
      float bs = first ? bias0[gcol] : bias1[gcol - splitN];
#pragma unroll
      for (int i = 0; i < 4; ++i) {
        size_t idx0 = (size_t)(grow + i) * ldc0 + gcol;
        if (EPI == 6) {
          float v6 = acc[m][n][i] + b2f(C0[idx0]);
          C0[idx0] = f2b(fmaxf(v6, 0.0f));
        } else {
          float v = acc[m][n][i] + bs;
          if (EPI == 1 || (EPI == 3 && first)) v = fmaxf(v, 0.0f);
          if (first)
            C0[idx0] = f2b(v);
          else
            C1[(size_t)(grow + i) * ldc1 + (gcol - splitN)] = f2b(v);
        }
      }
    }
  }
}

// ---- K-split GEMM (proven) ----
__global__ __launch_bounds__(256)
void gemm_ks(const uint16_t* __restrict__ A, int lda,
             const uint16_t* __restrict__ W, int Wld,
             float* __restrict__ P, int N,
             int Nt, int Khalf) {
  __shared__ uint16_t As[128 * 64];
  __shared__ uint16_t Ws[128 * 64];
  int bg = gridDim.x >> 1;
  int half = blockIdx.x >= bg;
  int bid = blockIdx.x - half * bg;
  int mtile = bid / Nt;
  int ntile = bid - mtile * Nt;
  const int row0 = mtile << 7, col0 = ntile << 7;
  const int t = threadIdx.x;
  const int w = t >> 6, l = t & 63;
  const int wr = w >> 1, wc = w & 1;
  const int sr = l >> 3, scg = l & 7;
  const int fr = l & 15, fq = l >> 4;

  f32x4 acc[4][4] = {};

  const uint16_t* Ab = A + half * Khalf;
  const uint16_t* Wb = W + half * Khalf;
  const uint16_t* Wbase = Wb + (size_t)(col0 + w * 32 + sr) * Wld + scg * 8;
  const uint16_t* Abase0 = Ab + (size_t)(row0 + w * 32 + sr) * lda + scg * 8;

  for (int k0 = 0; k0 < Khalf; k0 += 64) {
#pragma unroll
    for (int j = 0; j < 4; ++j)
      gload_lds16(Abase0 + (size_t)(j * 8) * lda + k0, &As[(w * 32 + j * 8) * 64]);
#pragma unroll
    for (int j = 0; j < 4; ++j)
      gload_lds16(Wbase + (size_t)(j * 8) * Wld + k0, &Ws[(w * 32 + j * 8) * 64]);
    __syncthreads();
#pragma unroll
    for (int ks = 0; ks < 2; ++ks) {
      s16x8 fa[4], fb[4];
#pragma unroll
      for (int m = 0; m < 4; ++m)
        fa[m] = *(const s16x8*)&As[(wr * 64 + m * 16 + fr) * 64 + ks * 32 + fq * 8];
#pragma unroll
      for (int n = 0; n < 4; ++n)
        fb[n] = *(const s16x8*)&Ws[(wc * 64 + n * 16 + fr) * 64 + ks * 32 + fq * 8];
#pragma unroll
      for (int m = 0; m < 4; ++m)
#pragma unroll
        for (int n = 0; n < 4; ++n)
          acc[m][n] = __builtin_amdgcn_mfma_f32_16x16x32_bf16(fa[m], fb[n], acc[m][n], 0, 0, 0);
    }
    __syncthreads();
  }

  float* Pf = P + (size_t)half * B_SZ * N;
#pragma unroll
  for (int m = 0; m < 4; ++m) {
    int grow = row0 + wr * 64 + m * 16 + fq * 4;
#pragma unroll
    for (int n = 0; n < 4; ++n) {
      int gcol = col0 + wc * 64 + n * 16 + fr;
#pragma unroll
      for (int i = 0; i < 4; ++i)
        Pf[(size_t)(grow + i) * N + gcol] = acc[m][n][i];
    }
  }
}

// ---- Dual K-split GEMM: pair-bit selects {A0,W0,P} vs {A1,W1,P+2*B*N}.
// Both pairs share geometry (N, Nt, Khalf, lda, Wld). Same loop text as gemm_ks.
__global__ __launch_bounds__(256)
void gemm_ks2(const uint16_t* __restrict__ Aa, const uint16_t* __restrict__ Ab2,
              int lda,
              const uint16_t* __restrict__ Wa, const uint16_t* __restrict__ Wb2,
              int Wld,
              float* __restrict__ P, int N,
              int Nt, int Khalf) {
  __shared__ uint16_t As[128 * 64];
  __shared__ uint16_t Ws[128 * 64];
  int bg2 = gridDim.x >> 1;
  int pair = blockIdx.x >= bg2;
  int bidp = blockIdx.x - pair * bg2;
  int bg = bg2 >> 1;
  int half = bidp >= bg;
  int bid = bidp - half * bg;
  int mtile = bid / Nt;
  int ntile = bid - mtile * Nt;
  const int row0 = mtile << 7, col0 = ntile << 7;
  const int t = threadIdx.x;
  const int w = t >> 6, l = t & 63;
  const int wr = w >> 1, wc = w & 1;
  const int sr = l >> 3, scg = l & 7;
  const int fr = l & 15, fq = l >> 4;

  f32x4 acc[4][4] = {};

  const uint16_t* A = pair ? Ab2 : Aa;
  const uint16_t* W = pair ? Wb2 : Wa;
  const uint16_t* Ab = A + half * Khalf;
  const uint16_t* Wb = W + half * Khalf;
  const uint16_t* Wbase = Wb + (size_t)(col0 + w * 32 + sr) * Wld + scg * 8;
  const uint16_t* Abase0 = Ab + (size_t)(row0 + w * 32 + sr) * lda + scg * 8;

  for (int k0 = 0; k0 < Khalf; k0 += 64) {
#pragma unroll
    for (int j = 0; j < 4; ++j)
      gload_lds16(Abase0 + (size_t)(j * 8) * lda + k0, &As[(w * 32 + j * 8) * 64]);
#pragma unroll
    for (int j = 0; j < 4; ++j)
      gload_lds16(Wbase + (size_t)(j * 8) * Wld + k0, &Ws[(w * 32 + j * 8) * 64]);
    __syncthreads();
#pragma unroll
    for (int ks = 0; ks < 2; ++ks) {
      s16x8 fa[4], fb[4];
#pragma unroll
      for (int m = 0; m < 4; ++m)
        fa[m] = *(const s16x8*)&As[(wr * 64 + m * 16 + fr) * 64 + ks * 32 + fq * 8];
#pragma unroll
      for (int n = 0; n < 4; ++n)
        fb[n] = *(const s16x8*)&Ws[(wc * 64 + n * 16 + fr) * 64 + ks * 32 + fq * 8];
#pragma unroll
      for (int m = 0; m < 4; ++m)
#pragma unroll
        for (int n = 0; n < 4; ++n)
          acc[m][n] = __builtin_amdgcn_mfma_f32_16x16x32_bf16(fa[m], fb[n], acc[m][n], 0, 0, 0);
    }
    __syncthreads();
  }

  float* Pf = P + (size_t)pair * 2 * B_SZ * N + (size_t)half * B_SZ * N;
#pragma unroll
  for (int m = 0; m < 4; ++m) {
    int grow = row0 + wr * 64 + m * 16 + fq * 4;
#pragma unroll
    for (int n = 0; n < 4; ++n) {
      int gcol = col0 + wc * 64 + n * 16 + fr;
#pragma unroll
      for (int i = 0; i < 4; ++i)
        Pf[(size_t)(grow + i) * N + gcol] = acc[m][n][i];
    }
  }
}

// combiner: dst = bf16(P0 + P1 + bias), N power of two
__global__ __launch_bounds__(256)
void combine2(const float* __restrict__ P, const float* __restrict__ bias,
              uint16_t* __restrict__ dst, int N, int total4) {
  int i = blockIdx.x * 256 + threadIdx.x;
  if (i >= total4) return;
  size_t idx = (size_t)i * 4;
  const float* P1 = P + (size_t)B_SZ * N;
  f32x4 a = *(const f32x4*)(P + idx);
  f32x4 b = *(const f32x4*)(P1 + idx);
  int col = (int)(idx & (size_t)(N - 1));
#pragma unroll
  for (int k = 0; k < 4; ++k)
    dst[idx + k] = f2b(a[k] + b[k] + bias[col + k]);
}

// combine2z: enc2-combiner fused with reparameterization (R24-proven).
__global__ __launch_bounds__(256)
void combine2z(const float* __restrict__ P, const float* __restrict__ bias,
               const float* __restrict__ eps,
               uint16_t* __restrict__ estats,
               float* __restrict__ oz, float* __restrict__ omu, float* __restrict__ olq,
               uint16_t* __restrict__ xza) {
  int i = blockIdx.x * 256 + threadIdx.x;  // B*Z
  int b = i >> 8, j = i & 255;
  const float* P1 = P + (size_t)B_SZ * 512;
  size_t i0 = (size_t)b * 512 + j;
  size_t i1 = i0 + 256;
  float mu = P[i0] + P1[i0] + bias[j];
  float lq = P[i1] + P1[i1] + bias[j + 256];
  estats[i0] = f2b(mu);
  estats[i1] = f2b(lq);
  float lqc = clip10(lq);
  float z = mu + eps[i] * __expf(0.5f * lqc);
  oz[i] = z; omu[i] = mu; olq[i] = lqc;
  xza[(size_t)b * 832 + 512 + j] = f2b(z);
}

__device__ __forceinline__ float block_sum256(float v) {
  __shared__ float ps[4];
#pragma unroll
  for (int o = 32; o > 0; o >>= 1) v += __shfl_xor(v, o, 64);
  int l = threadIdx.x & 63, w = threadIdx.x >> 6;
  if (l == 0) ps[w] = v;
  __syncthreads();
  float r = ps[0] + ps[1] + ps[2] + ps[3];
  __syncthreads();
  return r;
}

// ---------------- epilogue: GRU + nll + kl ----------------
__global__ __launch_bounds__(256)
void gru_fused_t1(const uint16_t* __restrict__ gi, int ldgi,
                  const uint16_t* __restrict__ gh, int ldgh,
                  const float* __restrict__ hp, const float* __restrict__ x,
                  const uint16_t* __restrict__ dec, const uint16_t* __restrict__ pst,
                  const uint16_t* __restrict__ es,
                  float* __restrict__ out_h, float* __restrict__ out_nll,
                  float* __restrict__ out_kl) {
  int b = blockIdx.x, t = threadIdx.x;
  size_t gbi = (size_t)b * ldgi + (size_t)t * 8;
  size_t gbh = (size_t)b * ldgh + (size_t)t * 8;
  s16x8 ir = *(const s16x8*)(gi + gbi);
  s16x8 iz = *(const s16x8*)(gi + gbi + 2048);
  s16x8 inn = *(const s16x8*)(gi + gbi + 4096);
  s16x8 hr = *(const s16x8*)(gh + gbh);
  s16x8 hz = *(const s16x8*)(gh + gbh + 2048);
  s16x8 hn = *(const s16x8*)(gh + gbh + 4096);
  size_t hbase = (size_t)b * 2048 + (size_t)t * 8;
  f32x4 h0 = *(const f32x4*)(hp + hbase);
  f32x4 h1v = *(const f32x4*)(hp + hbase + 4);
  f32x4 o0, o1;
#pragma unroll
  for (int e = 0; e < 8; ++e) {
    float r = 1.f / (1.f + __expf(-(b2f((uint16_t)ir[e]) + b2f((uint16_t)hr[e]))));
    float zg = 1.f / (1.f + __expf(-(b2f((uint16_t)iz[e]) + b2f((uint16_t)hz[e]))));
    float nv = b2f((uint16_t)inn[e]) + r * b2f((uint16_t)hn[e]);
    float t2 = __expf(-2.f * fabsf(nv));
    float n = (1.f - t2) / (1.f + t2);
    n = (nv >= 0.f) ? n : -n;
    float hv = (e < 4) ? h0[e] : h1v[e - 4];
    float o = (1.f - zg) * n + zg * hv;
    if (e < 4) o0[e] = o; else o1[e - 4] = o;
  }
  *(f32x4*)(out_h + hbase) = o0;
  *(f32x4*)(out_h + hbase + 4) = o1;

  float s = 0.f;
#pragma unroll
  for (int rr = 0; rr < 2; ++rr) {
    int j = t + rr * 256;
    float mu = b2f(dec[(size_t)b * 1024 + j]);
    float lx = clip10(b2f(dec[(size_t)b * 1024 + 512 + j]));
    float d = x[(size_t)b * 512 + j] - mu;
    s += d * d * __expf(-lx) + lx;
  }
  s = block_sum256(s);
  if (t == 0) out_nll[b] = 0.5f * s;

  float mu_p = b2f(pst[(size_t)b * 512 + t]);
  float lp = b2f(pst[(size_t)b * 512 + 256 + t]);
  float mu_q = b2f(es[(size_t)b * 512 + t]);
  float lq = clip10(b2f(es[(size_t)b * 512 + 256 + t]));
  float dq = mu_q - mu_p;
  float enl = __expf(-lp);
  float kv = dq * dq * enl + __expf(lq) * enl + (lp - lq) - 1.0f;
  kv = block_sum256(kv);
  if (t == 0) out_kl[b] = 0.5f * kv;
}

// ================= tier 2 fallback: naive fp32 sliced pipeline =================
template <int MODE>
__global__ __launch_bounds__(256)
void gemm_nv(const float* __restrict__ A0, int ld0, int s1,
             const float* __restrict__ A1, int ld1, int s2,
             const float* __restrict__ A2, int ld2,
             const float* __restrict__ W, const float* __restrict__ bias,
             float* __restrict__ C, int N, int K) {
  int nb = N >> 8;
  int m = blockIdx.x / nb;
  int n = (blockIdx.x - m * nb) * 256 + threadIdx.x;
  const float* w = W + (size_t)n * K;
  float acc = 0.f;
  int k = 0;
  for (; k < s1; ++k) acc += A0[(size_t)m * ld0 + k] * w[k];
  for (; k < s2; ++k) acc += A1[(size_t)m * ld1 + (k - s1)] * w[k];
  for (; k < K; ++k) acc += A2[(size_t)m * ld2 + (k - s2)] * w[k];
  acc += bias[n];
  if (MODE == 1) acc = fmaxf(acc, 0.f);
  C[(size_t)m * N + n] = acc;
}

__global__ void z_nv(const float* __restrict__ ests, const float* __restrict__ eps,
                     float* __restrict__ oz, float* __restrict__ omu,
                     float* __restrict__ olq, float* __restrict__ zs, int row0, int nR) {
  int i = blockIdx.x * 256 + threadIdx.x;
  if (i >= nR * 256) return;
  int bl = i >> 8, j = i & 255;
  size_t g = (size_t)(row0 + bl) * 256 + j;
  float mu = ests[(size_t)bl * 512 + j];
  float lq = clip10(ests[(size_t)bl * 512 + 256 + j]);
  float z = mu + eps[g] * __expf(0.5f * lq);
  oz[g] = z; omu[g] = mu; olq[g] = lq;
  zs[(size_t)bl * 256 + j] = z;
}

__global__ void nll_nv(const float* __restrict__ x, const float* __restrict__ decs,
                       float* __restrict__ out, int row0) {
  int bl = blockIdx.x, l = threadIdx.x;
  int gb = row0 + bl;
  float s = 0.f;
  for (int j = l; j < 512; j += 64) {
    float mu = decs[(size_t)bl * 1024 + j];
    float lx = clip10(decs[(size_t)bl * 1024 + 512 + j]);
    float d = x[(size_t)gb * 512 + j] - mu;
    s += d * d * __expf(-lx) + lx;
  }
#pragma unroll
  for (int o = 32; o > 0; o >>= 1) s += __shfl_xor(s, o, 64);
  if (l == 0) out[gb] = 0.5f * s;
}

__global__ void kl_nv(const float* __restrict__ psts, const float* __restrict__ ests,
                      float* __restrict__ out, int row0) {
  int bl = blockIdx.x, l = threadIdx.x;
  int gb = row0 + bl;
  float s = 0.f;
  for (int j = l; j < 256; j += 64) {
    float mu_p = psts[(size_t)bl * 512 + j];
    float lp = psts[(size_t)bl * 512 + 256 + j];
    float mu_q = ests[(size_t)bl * 512 + j];
    float lq = clip10(ests[(size_t)bl * 512 + 256 + j]);
    float d = mu_q - mu_p;
    float enl = __expf(-lp);
    s += d * d * enl + __expf(lq) * enl + (lp - lq) - 1.0f;
  }
#pragma unroll
  for (int o = 32; o > 0; o >>= 1) s += __shfl_xor(s, o, 64);
  if (l == 0) out[gb] = 0.5f * s;
}

__global__ void gru_nv(const float* __restrict__ gis, const float* __restrict__ ghs,
                       const float* __restrict__ hp, float* __restrict__ ho,
                       int row0, int nR) {
  int i = blockIdx.x * 256 + threadIdx.x;
  if (i >= nR * 2048) return;
  int bl = i >> 11, j = i & 2047;
  size_t lb = (size_t)bl * 6144 + j;
  float r = 1.f / (1.f + __expf(-(gis[lb] + ghs[lb])));
  float zg = 1.f / (1.f + __expf(-(gis[lb + 2048] + ghs[lb + 2048])));
  float nv = gis[lb + 4096] + r * ghs[lb + 4096];
  float t2 = __expf(-2.f * fabsf(nv));
  float n = (1.f - t2) / (1.f + t2);
  n = (nv >= 0.f) ? n : -n;
  size_t g = (size_t)(row0 + bl) * 2048 + j;
  ho[g] = (1.f - zg) * n + zg * hp[g];
}

// ---------------- host ----------------
extern "C" void kernel_launch(void* const* d_in, const int* in_sizes, int n_in,
                              void* d_out, int out_size, void* d_ws, size_t ws_size,
                              hipStream_t stream) {
  const float* x_t = (const float*)d_in[0];
  const float* a_prev = (const float*)d_in[1];
  const float* h_prev = (const float*)d_in[2];
  const float* eps = (const float*)d_in[3];
  const float* prior_w1 = (const float*)d_in[4];
  const float* prior_b1 = (const float*)d_in[5];
  const float* prior_w2 = (const float*)d_in[6];
  const float* prior_b2 = (const float*)d_in[7];
  const float* enc_w1 = (const float*)d_in[8];
  const float* enc_b1 = (const float*)d_in[9];
  const float* enc_w2 = (const float*)d_in[10];
  const float* enc_b2 = (const float*)d_in[11];
  const float* dec_w1 = (const float*)d_in[12];
  const float* dec_b1 = (const float*)d_in[13];
  const float* dec_w2 = (const float*)d_in[14];
  const float* dec_b2 = (const float*)d_in[15];
  const float* w_ih = (const float*)d_in[16];
  const float* w_hh = (const float*)d_in[17];
  const float* b_ih = (const float*)d_in[18];
  const float* b_hh = (const float*)d_in[19];

  float* out = (float*)d_out;
  float* out_h = out;
  float* out_nll = out + (size_t)B_SZ * H_SZ;
  float* out_kl = out_nll + B_SZ;
  float* out_z = out_kl + B_SZ;
  float* out_mu = out_z + (size_t)B_SZ * Z_SZ;
  float* out_lq = out_mu + (size_t)B_SZ * Z_SZ;

  char* ws = (char*)d_ws;
  size_t off = 0;
  auto alloc = [&](size_t bytes) {
    void* p = ws + off;
    off += (bytes + 255) & ~(size_t)255;
    return p;
  };

  const size_t T1_DEMAND = 196500000;  // layout sums to 196,395,008 (proven avail)

  if (ws_size >= T1_DEMAND) {
    // =========== tier 1 ===========
    uint16_t* wmega = (uint16_t*)alloc((size_t)12288 * 2048 * 2);  // dead after mega
    uint16_t* wih = (uint16_t*)alloc((size_t)6144 * 832 * 2);
    uint16_t* wx_enc = (uint16_t*)alloc((size_t)2048 * 512 * 2);
    uint16_t* wz_dec = (uint16_t*)alloc((size_t)2048 * 256 * 2);
    uint16_t* pw2 = (uint16_t*)alloc((size_t)512 * 2048 * 2);
    uint16_t* ew2 = (uint16_t*)alloc((size_t)512 * 2048 * 2);
    uint16_t* dw2 = (uint16_t*)alloc((size_t)1024 * 2048 * 2);
    uint16_t* xza = (uint16_t*)alloc((size_t)B_SZ * 832 * 2);     // [x|z|a] concat
    uint16_t* hbuf = (uint16_t*)alloc((size_t)B_SZ * 2048 * 2);   // dead after mega
    uint16_t* megaC = (uint16_t*)alloc((size_t)B_SZ * 12288 * 2); // [h1p|gh|ench|dech]
    float* biascat = (float*)alloc(12288 * 4);
    // overlays (stream-ordered safe):
    float* Pbuf = (float*)wmega;                // K-split partials (<=33.6MB), pre-gi
    uint16_t* gi = wmega;                       // written after last Pbuf use
    uint16_t* pstats = hbuf;                    // after mega
    uint16_t* estats = hbuf + (size_t)2097152;
    uint16_t* decout = pw2;                     // pw2+ew2+dw2 span (dead/post-read)

    // ---- single fused conversion launch (13 segments) ----
    MC mc;
    int nseg = 0, acc = 0;
    auto seg = [&](const float* s, uint16_t* d, int R, int C, int sld, int dld) {
      mc.src[nseg] = s; mc.dst[nseg] = d; mc.c8[nseg] = C / 8;
      mc.sld[nseg] = sld; mc.dld[nseg] = dld; mc.base[nseg] = acc;
      acc += R * (C / 8); ++nseg;
    };
    seg(prior_w1, wmega, 2048, 2048, 2048, 2048);
    seg(w_hh, wmega + (size_t)2048 * 2048, 6144, 2048, 2048, 2048);
    seg(enc_w1 + 512, wmega + (size_t)8192 * 2048, 2048, 2048, 2560, 2048);
    seg(dec_w1 + 256, wmega + (size_t)10240 * 2048, 2048, 2048, 2304, 2048);
    seg(enc_w1, wx_enc, 2048, 512, 2560, 512);
    seg(dec_w1, wz_dec, 2048, 256, 2304, 256);
    seg(prior_w2, pw2, 512, 2048, 2048, 2048);
    seg(enc_w2, ew2, 512, 2048, 2048, 2048);
    seg(dec_w2, dw2, 1024, 2048, 2048, 2048);
    seg(w_ih, wih, 6144, 832, 832, 832);
    seg(x_t, xza, B_SZ, 512, 512, 832);
    seg(a_prev, xza + 768, B_SZ, 64, 64, 832);
    seg(h_prev, hbuf, B_SZ, 2048, 2048, 2048);
    mc.base[nseg] = acc;
    multiconv<<<dim3((acc + 255) / 256), dim3(256), 0, stream>>>(mc, nseg, acc);
    biascat_kernel<<<dim3(48), dim3(256), 0, stream>>>(prior_b1, b_hh, enc_b1, dec_b1, biascat);

    // mega: megaC[4096,12288] = h @ wmega^T + biascat (relu cols<2048), 8-phase
    gemm8p<<<dim3((B_SZ / 256) * 48), dim3(512), 0, stream>>>(
        hbuf, 2048, wmega, biascat, megaC, 12288, 2048, 48, 2048);
    // enc1x: relu(x @ wx^T + ench_partial) in-place at megaC+8192 (EPI6)
    gemm_bt<6><<<dim3((B_SZ / 128) * 16), dim3(256), 0, stream>>>(
        xza, 832, 512, xza, 832, 512, xza, 832, wx_enc,
        enc_b1, enc_b1, megaC + 8192, 12288, 2048, megaC + 8192, 12288, 16, 512);
    // prior2 + enc2 fused dual K-split (512 blocks):
    //   pair0: A=megaC cols0.., W=pw2 -> Pbuf[0..2)
    //   pair1: A=megaC cols8192.., W=ew2 -> Pbuf[2..4)
    gemm_ks2<<<dim3((B_SZ / 128) * 4 * 2 * 2), dim3(256), 0, stream>>>(
        megaC, megaC + 8192, 12288, pw2, ew2, 2048, Pbuf, 512, 4, 1024);
    combine2<<<dim3(B_SZ * 512 / 4 / 256), dim3(256), 0, stream>>>(
        Pbuf, prior_b2, pstats, 512, B_SZ * 512 / 4);
    combine2z<<<dim3(B_SZ * Z_SZ / 256), dim3(256), 0, stream>>>(
        Pbuf + (size_t)2 * B_SZ * 512, enc_b2, eps, estats,
        out_z, out_mu, out_lq, xza);
    // dec1x: relu(z @ wz^T + dech_partial) in-place at megaC+10240 (EPI6)
    gemm_bt<6><<<dim3((B_SZ / 128) * 16), dim3(256), 0, stream>>>(
        xza + 512, 832, 256, xza + 512, 832, 256, xza + 512, 832, wz_dec,
        dec_b1, dec_b1, megaC + 10240, 12288, 2048, megaC + 10240, 12288, 16, 256);
    // dec2 (K-split x2) -> decout
    gemm_ks<<<dim3((B_SZ / 128) * 8 * 2), dim3(256), 0, stream>>>(
        megaC + 10240, 12288, dw2, 2048, Pbuf, 1024, 8, 1024);
    combine2<<<dim3(B_SZ * 1024 / 4 / 256), dim3(256), 0, stream>>>(
        Pbuf, dec_b2, decout, 1024, B_SZ * 1024 / 4);
    // gi: xza @ w_ih^T + b via gemm_bt (1536 blocks; R21-proven shape)
    gemm_bt<2><<<dim3((B_SZ / 128) * 48), dim3(256), 0, stream>>>(
        xza, 832, 832, xza, 832, 832, xza, 832, wih,
        b_ih, b_ih, gi, 6144, 6144, gi, 6144, 48, 832);
    // epilogue: gh lives at megaC cols 2048.. (stride 12288)
    gru_fused_t1<<<dim3(B_SZ), dim3(256), 0, stream>>>(
        gi, 6144, megaC + 2048, 12288, h_prev, x_t, decout, pstats, estats,
        out_h, out_nll, out_kl);
  } else {
    // =========== tier 2: naive fp32 sliced ===========
    int R = 512;
    while (R > 32 && (size_t)R * 66560 + 4096 > ws_size) R >>= 1;
    float* h1s = (float*)alloc((size_t)R * 2048 * 4);
    float* psts = (float*)alloc((size_t)R * 512 * 4);
    float* ests = (float*)alloc((size_t)R * 512 * 4);
    float* decs = (float*)alloc((size_t)R * 1024 * 4);
    float* zs = (float*)alloc((size_t)R * 256 * 4);
    float* gis = (float*)alloc((size_t)R * 6144 * 4);
    float* ghs = (float*)alloc((size_t)R * 6144 * 4);
    const float* dummy = x_t;

    auto nv = [&](const float* A0, int ld0, int s1, const float* A1, int ld1, int s2,
                  const float* A2, int ld2, const float* W, const float* bias,
                  float* C, int M, int N, int K, int relu) {
      dim3 grid(M * (N / 256));
      if (relu)
        gemm_nv<1><<<grid, dim3(256), 0, stream>>>(A0, ld0, s1, A1, ld1, s2, A2, ld2, W, bias, C, N, K);
      else
        gemm_nv<0><<<grid, dim3(256), 0, stream>>>(A0, ld0, s1, A1, ld1, s2, A2, ld2, W, bias, C, N, K);
    };

    for (int s = 0; s < B_SZ / R; ++s) {
      int r0 = s * R;
      const float* xs = x_t + (size_t)r0 * 512;
      const float* hs = h_prev + (size_t)r0 * 2048;
      const float* as = a_prev + (size_t)r0 * 64;
      nv(hs, 2048, 2048, dummy, 0, 2048, dummy, 0, prior_w1, prior_b1, h1s, R, 2048, 2048, 1);
      nv(h1s, 2048, 2048, dummy, 0, 2048, dummy, 0, prior_w2, prior_b2, psts, R, 512, 2048, 0);
      nv(xs, 512, 512, hs, 2048, 2560, dummy, 0, enc_w1, enc_b1, h1s, R, 2048, 2560, 1);
      nv(h1s, 2048, 2048, dummy, 0, 2048, dummy, 0, enc_w2, enc_b2, ests, R, 512, 2048, 0);
      z_nv<<<dim3((R * 256 + 255) / 256), dim3(256), 0, stream>>>(
          ests, eps, out_z, out_mu, out_lq, zs, r0, R);
      nv(zs, 256, 256, hs, 2048, 2304, dummy, 0, dec_w1, dec_b1, h1s, R, 2048, 2304, 1);
      nv(h1s, 2048, 2048, dummy, 0, 2048, dummy, 0, dec_w2, dec_b2, decs, R, 1024, 2048, 0);
      nv(hs, 2048, 2048, dummy, 0, 2048, dummy, 0, w_hh, b_hh, ghs, R, 6144, 2048, 0);
      nv(xs, 512, 512, zs, 256, 768, as, 64, w_ih, b_ih, gis, R, 6144, 832, 0);
      nll_nv<<<dim3(R), dim3(64), 0, stream>>>(x_t, decs, out_nll, r0);
      kl_nv<<<dim3(R), dim3(64), 0, stream>>>(psts, ests, out_kl, r0);
      gru_nv<<<dim3((R * 2048 + 255) / 256), dim3(256), 0, stream>>>(
          gis, ghs, h_prev, out_h, r0, R);
    }
  }
}